// Round 22
// baseline (176.395 us; speedup 1.0000x reference)
//
#include <hip/hip_runtime.h>

// ProbSparse attention (Informer) — B=4, L=2048, D=512, H=8, DK=64, SK=NTOP=40
// Round 19: gemm_proj K-loop -> double-buffered single-barrier schedule
// (T3 "minimum 2-phase": prefetch next tile BEFORE compute, one
// __syncthreads()/K-step whose implicit vmcnt(0) drains after MFMA covered
// the load latency). LDS 32->64KB (2 blocks/CU). gemm_out unchanged (control).
// Everything else bit-identical to R18.

typedef unsigned short u16;
typedef unsigned long long u64;
typedef __attribute__((ext_vector_type(8))) short short8;
typedef __attribute__((ext_vector_type(4))) float f32x4;

constexpr int NB = 4;       // batch
constexpr int SEQ = 2048;   // L
constexpr int DM = 512;     // D
constexpr int NH = 8;
constexpr int DH = 64;      // DK
constexpr int NS = 40;      // SK (samples)
constexpr int NT = 40;      // NTOP
constexpr int ROWS = NB * SEQ;          // 8192
constexpr int BHROWS = NB * NH * SEQ;   // 65536
constexpr int NSC = 8;      // s-chunks in pv (SEQ/256)
constexpr int VCH = 16;     // vsum l-chunks per (b,h)
constexpr int UG = 20;      // u's per pv block (40/2)

// ---------------------------------------------------------------------------
// bf16 helpers (round-to-nearest-even)
// ---------------------------------------------------------------------------
__device__ __forceinline__ u16 f2bf(float x) {
  union { float f; unsigned u; } v; v.f = x;
  unsigned r = v.u + 0x7FFFu + ((v.u >> 16) & 1u);
  return (u16)(r >> 16);
}
__device__ __forceinline__ float bf2f(u16 b) {
  union { unsigned u; float f; } v; v.u = ((unsigned)b) << 16;
  return v.f;
}

__device__ __forceinline__ void gload16(void* lds, const void* g) {
  __builtin_amdgcn_global_load_lds(
      (const __attribute__((address_space(1))) unsigned int*)g,
      (__attribute__((address_space(3))) unsigned int*)lds, 16, 0, 0);
}

// ---------------------------------------------------------------------------
// Merged conversions. z=0..2: X->bf16 (q hi+lo, k hi+lo, v hi).
// z=3, blockIdx.x<256: W [k][n] fp32 -> [n][k] bf16 (Wq/Wk hi+lo, Wv/Wo hi).
// ---------------------------------------------------------------------------
__global__ __launch_bounds__(256) void cvt_all(const float* __restrict__ q,
                                               const float* __restrict__ k,
                                               const float* __restrict__ v,
                                               const float* __restrict__ Wq,
                                               const float* __restrict__ Wk,
                                               const float* __restrict__ Wv,
                                               const float* __restrict__ Wo,
                                               u16* __restrict__ QXH, u16* __restrict__ QXL,
                                               u16* __restrict__ KXH, u16* __restrict__ KXL,
                                               u16* __restrict__ VXH,
                                               u16* __restrict__ WqH, u16* __restrict__ WqL,
                                               u16* __restrict__ WkH, u16* __restrict__ WkL,
                                               u16* __restrict__ WvH, u16* __restrict__ WoH) {
  __shared__ float T[64][65];
  const int z = blockIdx.z, t = threadIdx.x;
  if (z < 3) {
    const int i = blockIdx.x * 256 + t;
    const float* X = (z == 0) ? q : (z == 1) ? k : v;
    u16* H = (z == 0) ? QXH : (z == 1) ? KXH : VXH;
    u16* L = (z == 0) ? QXL : KXL;
    float4 val = ((const float4*)X)[i];
    ushort4 h;
    h.x = f2bf(val.x); h.y = f2bf(val.y); h.z = f2bf(val.z); h.w = f2bf(val.w);
    ((ushort4*)H)[i] = h;
    if (z < 2) {
      ushort4 l;
      l.x = f2bf(val.x - bf2f(h.x)); l.y = f2bf(val.y - bf2f(h.y));
      l.z = f2bf(val.z - bf2f(h.z)); l.w = f2bf(val.w - bf2f(h.w));
      ((ushort4*)L)[i] = l;
    }
    return;
  }
  if (blockIdx.x >= 256) return;
  const int wz = blockIdx.x >> 6;
  const int c0 = (blockIdx.x & 7) * 64;
  const int r0 = ((blockIdx.x >> 3) & 7) * 64;
  const float* W = (wz == 0) ? Wq : (wz == 1) ? Wk : (wz == 2) ? Wv : Wo;
  u16* H = (wz == 0) ? WqH : (wz == 1) ? WkH : (wz == 2) ? WvH : WoH;
  u16* L = (wz == 0) ? WqL : WkL;
  const int doLo = (wz < 2);
  const int lr = t >> 4, lc4 = (t & 15) * 4;
#pragma unroll
  for (int i = 0; i < 4; i++) {
    float4 val = *(const float4*)&W[(size_t)(r0 + lr + i * 16) * DM + c0 + lc4];
    T[lr + i * 16][lc4 + 0] = val.x;
    T[lr + i * 16][lc4 + 1] = val.y;
    T[lr + i * 16][lc4 + 2] = val.z;
    T[lr + i * 16][lc4 + 3] = val.w;
  }
  __syncthreads();
#pragma unroll
  for (int i = 0; i < 4; i++) {
    const int n = lr + i * 16;
    float x0 = T[lc4 + 0][n], x1 = T[lc4 + 1][n], x2 = T[lc4 + 2][n], x3 = T[lc4 + 3][n];
    ushort4 h;
    h.x = f2bf(x0); h.y = f2bf(x1); h.z = f2bf(x2); h.w = f2bf(x3);
    *(ushort4*)&H[(size_t)(c0 + n) * DM + r0 + lc4] = h;
    if (doLo) {
      ushort4 l;
      l.x = f2bf(x0 - bf2f(h.x)); l.y = f2bf(x1 - bf2f(h.y));
      l.z = f2bf(x2 - bf2f(h.z)); l.w = f2bf(x3 - bf2f(h.w));
      *(ushort4*)&L[(size_t)(c0 + n) * DM + r0 + lc4] = l;
    }
  }
}

// ---------------------------------------------------------------------------
// 128x128 GEMM body, DOUBLE-BUFFERED single-barrier K-loop (T3 minimum):
// prologue stage -> barrier -> { prefetch(next) ; ds_read+MFMA(cur) ;
// barrier } x16. LDS arrays are 2x sized; buf select via +cur*BUF.
// ---------------------------------------------------------------------------
template <bool SPLIT3, bool TOSPLIT>
__device__ __forceinline__ void gemm_body128(const u16* __restrict__ XH,
                                             const u16* __restrict__ XL,
                                             const u16* __restrict__ WTH,
                                             const u16* __restrict__ WTL,
                                             const float* __restrict__ bias,
                                             float* __restrict__ out,
                                             u16* Ah, u16* Al, u16* Bh, u16* Bl,
                                             int row0, int col0) {
  const int tid = threadIdx.x, lane = tid & 63, w = tid >> 6;
  const int wr = (w >> 1) * 64, wc = (w & 1) * 64;
  const int lr = lane & 15, kb8 = (lane >> 4) * 8;
  const int mrow = lane >> 2;
  const int kcol = (lane & 3) * 8;
  constexpr int PER = SPLIT3 ? 8 : 4;
  constexpr int BUF = 128 * 32;

  f32x4 acc[4][4];
#pragma unroll
  for (int i = 0; i < 4; i++)
#pragma unroll
    for (int j = 0; j < 4; j++) acc[i][j] = (f32x4){0.f, 0.f, 0.f, 0.f};

  auto stage = [&](int buf, int k0) {
#pragma unroll
    for (int i = 0; i < PER; i++) {
      const int c = w * PER + i;
      const u16* g;
      u16* l;
      if (SPLIT3) {
        if (c < 8)       { g = XH  + (size_t)(row0 + c * 16 + mrow) * DM + k0 + kcol;        l = Ah + buf * BUF + c * 512; }
        else if (c < 16) { g = XL  + (size_t)(row0 + (c - 8) * 16 + mrow) * DM + k0 + kcol;  l = Al + buf * BUF + (c - 8) * 512; }
        else if (c < 24) { g = WTH + (size_t)(col0 + (c - 16) * 16 + mrow) * DM + k0 + kcol; l = Bh + buf * BUF + (c - 16) * 512; }
        else             { g = WTL + (size_t)(col0 + (c - 24) * 16 + mrow) * DM + k0 + kcol; l = Bl + buf * BUF + (c - 24) * 512; }
      } else {
        if (c < 8)       { g = XH  + (size_t)(row0 + c * 16 + mrow) * DM + k0 + kcol;        l = Ah + buf * BUF + c * 512; }
        else             { g = WTH + (size_t)(col0 + (c - 8) * 16 + mrow) * DM + k0 + kcol;  l = Bh + buf * BUF + (c - 8) * 512; }
      }
      gload16(l, g);
    }
  };

  stage(0, 0);
  __syncthreads();   // drains prologue loads (implicit vmcnt(0))

  int cur = 0;
  for (int k0 = 0; k0 < DM; k0 += 32) {
    if (k0 + 32 < DM) stage(cur ^ 1, k0 + 32);   // prefetch next tile

    const int ob = cur * BUF;
    short8 ah[4], bh[4];
#pragma unroll
    for (int i = 0; i < 4; i++) ah[i] = *(const short8*)&Ah[ob + (wr + i * 16 + lr) * 32 + kb8];
#pragma unroll
    for (int j = 0; j < 4; j++) bh[j] = *(const short8*)&Bh[ob + (wc + j * 16 + lr) * 32 + kb8];
    if constexpr (SPLIT3) {
      short8 al[4], bl[4];
#pragma unroll
      for (int i = 0; i < 4; i++) al[i] = *(const short8*)&Al[ob + (wr + i * 16 + lr) * 32 + kb8];
#pragma unroll
      for (int j = 0; j < 4; j++) bl[j] = *(const short8*)&Bl[ob + (wc + j * 16 + lr) * 32 + kb8];
#pragma unroll
      for (int i = 0; i < 4; i++)
#pragma unroll
        for (int j = 0; j < 4; j++) {
          acc[i][j] = __builtin_amdgcn_mfma_f32_16x16x32_bf16(ah[i], bh[j], acc[i][j], 0, 0, 0);
          acc[i][j] = __builtin_amdgcn_mfma_f32_16x16x32_bf16(ah[i], bl[j], acc[i][j], 0, 0, 0);
          acc[i][j] = __builtin_amdgcn_mfma_f32_16x16x32_bf16(al[i], bh[j], acc[i][j], 0, 0, 0);
        }
    } else {
#pragma unroll
      for (int i = 0; i < 4; i++)
#pragma unroll
        for (int j = 0; j < 4; j++)
          acc[i][j] = __builtin_amdgcn_mfma_f32_16x16x32_bf16(ah[i], bh[j], acc[i][j], 0, 0, 0);
    }

    __syncthreads();   // joins waves + drains prefetch (vmcnt(0))
    cur ^= 1;
  }

#pragma unroll
  for (int i = 0; i < 4; i++)
#pragma unroll
    for (int j = 0; j < 4; j++) {
      const int col = col0 + wc + j * 16 + lr;
      const float bval = bias[col];
#pragma unroll
      for (int r = 0; r < 4; r++) {
        const int row = row0 + wr + i * 16 + (lane >> 4) * 4 + r;
        const float v = acc[i][j][r] + bval;
        if constexpr (TOSPLIT) {
          const int b = row >> 11, l2 = row & (SEQ - 1);
          const int h = col >> 6, dk = col & 63;
          out[((size_t)(b * NH + h) * SEQ + l2) * DH + dk] = v;
        } else {
          out[(size_t)row * DM + col] = v;
        }
      }
    }
}

// ---------------------------------------------------------------------------
// 128x64 GEMM body (unchanged 2-barrier structure; control).
// ---------------------------------------------------------------------------
template <bool SPLIT3, bool TOSPLIT>
__device__ __forceinline__ void gemm_body64(const u16* __restrict__ XH,
                                            const u16* __restrict__ XL,
                                            const u16* __restrict__ WTH,
                                            const u16* __restrict__ WTL,
                                            const float* __restrict__ bias,
                                            float* __restrict__ out,
                                            u16* Ah, u16* Al, u16* Bh, u16* Bl,
                                            int row0, int col0) {
  const int tid = threadIdx.x, lane = tid & 63, w = tid >> 6;
  const int wr = (w >> 1) * 64, wc = (w & 1) * 32;
  const int lr = lane & 15, kb8 = (lane >> 4) * 8;
  const int mrow = lane >> 2;
  const int kcol = (lane & 3) * 8;

  f32x4 acc[4][2];
#pragma unroll
  for (int i = 0; i < 4; i++)
#pragma unroll
    for (int j = 0; j < 2; j++) acc[i][j] = (f32x4){0.f, 0.f, 0.f, 0.f};

  constexpr int PER = SPLIT3 ? 6 : 3;

  for (int k0 = 0; k0 < DM; k0 += 32) {
    __syncthreads();
#pragma unroll
    for (int i = 0; i < PER; i++) {
      const int c = w * PER + i;
      const u16* g;
      u16* l;
      if (SPLIT3) {
        if (c < 8)       { g = XH  + (size_t)(row0 + c * 16 + mrow) * DM + k0 + kcol;        l = Ah + c * 512; }
        else if (c < 16) { g = XL  + (size_t)(row0 + (c - 8) * 16 + mrow) * DM + k0 + kcol;  l = Al + (c - 8) * 512; }
        else if (c < 20) { g = WTH + (size_t)(col0 + (c - 16) * 16 + mrow) * DM + k0 + kcol; l = Bh + (c - 16) * 512; }
        else             { g = WTL + (size_t)(col0 + (c - 20) * 16 + mrow) * DM + k0 + kcol; l = Bl + (c - 20) * 512; }
      } else {
        if (c < 8)       { g = XH  + (size_t)(row0 + c * 16 + mrow) * DM + k0 + kcol;        l = Ah + c * 512; }
        else             { g = WTH + (size_t)(col0 + (c - 8) * 16 + mrow) * DM + k0 + kcol;  l = Bh + (c - 8) * 512; }
      }
      gload16(l, g);
    }
    __syncthreads();

    short8 ah[4], bh[2];
#pragma unroll
    for (int i = 0; i < 4; i++) ah[i] = *(const short8*)&Ah[(wr + i * 16 + lr) * 32 + kb8];
#pragma unroll
    for (int j = 0; j < 2; j++) bh[j] = *(const short8*)&Bh[(wc + j * 16 + lr) * 32 + kb8];
    if constexpr (SPLIT3) {
      short8 al[4], bl[2];
#pragma unroll
      for (int i = 0; i < 4; i++) al[i] = *(const short8*)&Al[(wr + i * 16 + lr) * 32 + kb8];
#pragma unroll
      for (int j = 0; j < 2; j++) bl[j] = *(const short8*)&Bl[(wc + j * 16 + lr) * 32 + kb8];
#pragma unroll
      for (int i = 0; i < 4; i++)
#pragma unroll
        for (int j = 0; j < 2; j++) {
          acc[i][j] = __builtin_amdgcn_mfma_f32_16x16x32_bf16(ah[i], bh[j], acc[i][j], 0, 0, 0);
          acc[i][j] = __builtin_amdgcn_mfma_f32_16x16x32_bf16(ah[i], bl[j], acc[i][j], 0, 0, 0);
          acc[i][j] = __builtin_amdgcn_mfma_f32_16x16x32_bf16(al[i], bh[j], acc[i][j], 0, 0, 0);
        }
    } else {
#pragma unroll
      for (int i = 0; i < 4; i++)
#pragma unroll
        for (int j = 0; j < 2; j++)
          acc[i][j] = __builtin_amdgcn_mfma_f32_16x16x32_bf16(ah[i], bh[j], acc[i][j], 0, 0, 0);
    }
  }

#pragma unroll
  for (int i = 0; i < 4; i++)
#pragma unroll
    for (int j = 0; j < 2; j++) {
      const int col = col0 + wc + j * 16 + lr;
      const float bval = bias[col];
#pragma unroll
      for (int r = 0; r < 4; r++) {
        const int row = row0 + wr + i * 16 + (lane >> 4) * 4 + r;
        const float v = acc[i][j][r] + bval;
        if constexpr (TOSPLIT) {
          const int b = row >> 11, l2 = row & (SEQ - 1);
          const int h = col >> 6, dk = col & 63;
          out[((size_t)(b * NH + h) * SEQ + l2) * DH + dk] = v;
        } else {
          out[(size_t)row * DM + col] = v;
        }
      }
    }
}

// ---------------------------------------------------------------------------
// Merged projection GEMM (128x128, double-buffered): z=0 Q, z=1 K, z=2 V.
// ---------------------------------------------------------------------------
__global__ __launch_bounds__(256) void gemm_proj(const u16* __restrict__ QXH, const u16* __restrict__ QXL,
                                                 const u16* __restrict__ KXH, const u16* __restrict__ KXL,
                                                 const u16* __restrict__ VXH,
                                                 const u16* __restrict__ WqH, const u16* __restrict__ WqL,
                                                 const u16* __restrict__ WkH, const u16* __restrict__ WkL,
                                                 const u16* __restrict__ WvH,
                                                 const float* __restrict__ bq, const float* __restrict__ bk,
                                                 const float* __restrict__ bv,
                                                 float* __restrict__ Q, float* __restrict__ Kp,
                                                 float* __restrict__ Vp) {
  __shared__ __align__(16) u16 Ah[2 * 128 * 32];
  __shared__ __align__(16) u16 Al[2 * 128 * 32];
  __shared__ __align__(16) u16 Bh[2 * 128 * 32];
  __shared__ __align__(16) u16 Bl[2 * 128 * 32];
  const int row0 = blockIdx.x * 128, col0 = blockIdx.y * 128;
  if (blockIdx.z == 0)
    gemm_body128<true, true>(QXH, QXL, WqH, WqL, bq, Q, Ah, Al, Bh, Bl, row0, col0);
  else if (blockIdx.z == 1)
    gemm_body128<true, true>(KXH, KXL, WkH, WkL, bk, Kp, Ah, Al, Bh, Bl, row0, col0);
  else
    gemm_body128<false, true>(VXH, VXH, WvH, WvH, bv, Vp, Ah, Al, Bh, Bl, row0, col0);
}

// ---------------------------------------------------------------------------
// Output GEMM (128x64): CH bf16 @ WoH + bo -> out.
// ---------------------------------------------------------------------------
__global__ __launch_bounds__(256) void gemm_out(const u16* __restrict__ CH,
                                                const u16* __restrict__ WoH,
                                                const float* __restrict__ bo,
                                                float* __restrict__ out) {
  __shared__ __align__(16) u16 Ah[128 * 32];
  __shared__ __align__(16) u16 Al[128 * 32];
  __shared__ __align__(16) u16 Bh[64 * 32];
  __shared__ __align__(16) u16 Bl[64 * 32];
  gemm_body64<false, false>(CH, CH, WoH, WoH, bo, out, Ah, Al, Bh, Bl,
                            blockIdx.x * 128, blockIdx.y * 64);
}

// ---------------------------------------------------------------------------
// M[b,h,q]. One wave per row; idx via LDS; bijective XCD swizzle for K L2-res.
// ---------------------------------------------------------------------------
__global__ __launch_bounds__(256) void m_kernel(const float* __restrict__ Q,
                                                const float* __restrict__ K,
                                                const int* __restrict__ idxs,
                                                float* __restrict__ M) {
  __shared__ int idl[4 * NS];
  const int tid = threadIdx.x;
  const int x = blockIdx.x & 7;        // XCD
  const int slot = blockIdx.x >> 3;
  const int bh = x * 4 + (slot >> 9);  // 4 bh-slices per XCD
  const int q0 = (slot & 511) * 4;

  if (tid < 4 * NS) idl[tid] = idxs[q0 * NS + tid];
  __syncthreads();

  const int lane = tid & 63, wid = tid >> 6;
  const int r = bh * SEQ + q0 + wid;
  const int g = lane >> 3;
  const int d8 = (lane & 7) * 8;
  const float* Qr = Q + (size_t)r * DH + d8;
  const float4 q0v = *(const float4*)Qr;
  const float4 q1v = *(const float4*)(Qr + 4);
  const float* Kbh = K + (size_t)bh * SEQ * DH;

  int ks[5];
#pragma unroll
  for (int p = 0; p < 5; p++) ks[p] = idl[wid * NS + g + 8 * p];
  float4 k0[5], k1[5];
#pragma unroll
  for (int p = 0; p < 5; p++) {
    const float* Kr = Kbh + (size_t)ks[p] * DH + d8;
    k0[p] = *(const float4*)Kr;
    k1[p] = *(const float4*)(Kr + 4);
  }
  float mx = -1e30f, sm = 0.f;
#pragma unroll
  for (int p = 0; p < 5; p++) {
    float acc = q0v.x * k0[p].x + q0v.y * k0[p].y + q0v.z * k0[p].z + q0v.w * k0[p].w +
                q1v.x * k1[p].x + q1v.y * k1[p].y + q1v.z * k1[p].z + q1v.w * k1[p].w;
    acc += __shfl_xor(acc, 1, 64);
    acc += __shfl_xor(acc, 2, 64);
    acc += __shfl_xor(acc, 4, 64);
    mx = fmaxf(mx, acc);
    sm += acc;
  }
#pragma unroll
  for (int o = 8; o <= 32; o <<= 1) {
    mx = fmaxf(mx, __shfl_xor(mx, o, 64));
    sm += __shfl_xor(sm, o, 64);
  }
  if (lane == 0) M[r] = mx - sm * (1.0f / (float)SEQ);
}

// ---------------------------------------------------------------------------
// Top-40 per (b,h) via bitonic sort of packed u64 keys. 1024 thr per (b,h).
// ---------------------------------------------------------------------------
__global__ __launch_bounds__(1024) void topk_kernel(const float* __restrict__ M,
                                                    int* __restrict__ Mtop) {
  __shared__ u64 keys[SEQ];
  const int bh = blockIdx.x, tid = threadIdx.x;
  const float* Mb = M + (size_t)bh * SEQ;
#pragma unroll
  for (int i = tid; i < SEQ; i += 1024) {
    unsigned ub = __float_as_uint(Mb[i]);
    ub ^= (ub >> 31) ? 0xFFFFFFFFu : 0x80000000u;
    keys[i] = ((u64)ub << 32) | (u64)(unsigned)~i;
  }
  __syncthreads();
  for (int k = 2; k <= SEQ; k <<= 1) {
    for (int j = k >> 1; j > 0; j >>= 1) {
#pragma unroll
      for (int i = tid; i < SEQ; i += 1024) {
        const int partner = i ^ j;
        if (partner > i) {
          const u64 a = keys[i], b = keys[partner];
          const bool desc = ((i & k) == 0);
          if (desc ? (a < b) : (a > b)) { keys[i] = b; keys[partner] = a; }
        }
      }
      __syncthreads();
    }
  }
  if (tid < NT) Mtop[bh * NT + tid] = (int)~(unsigned)keys[tid];
}

// ---------------------------------------------------------------------------
// V_sum two-stage.
// ---------------------------------------------------------------------------
__global__ __launch_bounds__(256) void vsum1_kernel(const float* __restrict__ V,
                                                    float* __restrict__ part) {
  __shared__ float sm[4][DH];
  const int bh = blockIdx.x, c = blockIdx.y, tid = threadIdx.x;
  const int dk = tid & 63, p = tid >> 6;
  const float* Vb = V + ((size_t)bh * SEQ + c * (SEQ / VCH)) * DH;
  float s = 0.f;
  for (int l = p; l < SEQ / VCH; l += 4) s += Vb[(size_t)l * DH + dk];
  sm[p][dk] = s;
  __syncthreads();
  if (p == 0)
    part[(size_t)(bh * VCH + c) * DH + dk] = sm[0][dk] + sm[1][dk] + sm[2][dk] + sm[3][dk];
}

__global__ __launch_bounds__(64) void vsum2_kernel(const float* __restrict__ part,
                                                   float* __restrict__ Vsum) {
  const int bh = blockIdx.x, dk = threadIdx.x;
  float s = 0.f;
#pragma unroll
  for (int c = 0; c < VCH; c++) s += part[(size_t)(bh * VCH + c) * DH + dk];
  Vsum[bh * DH + dk] = s;
}

// ---------------------------------------------------------------------------
// CH (B,L,D) bf16: V_sum broadcast (selected rows overwritten later).
// ---------------------------------------------------------------------------
__global__ __launch_bounds__(256) void ctxinit_kernel(const float* __restrict__ Vsum,
                                                      u16* __restrict__ CH) {
  const int idx = blockIdx.x * 256 + threadIdx.x;
  const int f = idx * 4;
  const int d = f & (DM - 1), b = f >> 20;
  float4 v = *(const float4*)&Vsum[b * DM + d];
  ushort4 h;
  h.x = f2bf(v.x); h.y = f2bf(v.y); h.z = f2bf(v.z); h.w = f2bf(v.w);
  ((ushort4*)CH)[idx] = h;
}

// ---------------------------------------------------------------------------
// Fused scores+softmax-partial+PV. Block (bh, sc, ug): 256 s-rows, 20 u's.
// Unnormalized: El = exp(Q_red·K/8); dpart = per-u row-sums; updp = El@V.
// ---------------------------------------------------------------------------
__global__ __launch_bounds__(256) void pv_fused_kernel(const float* __restrict__ Q,
                                                       const float* __restrict__ K,
                                                       const float* __restrict__ V,
                                                       const int* __restrict__ Mtop,
                                                       float* __restrict__ updp,
                                                       float* __restrict__ dpart) {
  __shared__ float El[UG * 256];  // 20KB: exp'd scores [u_local][sj]
  __shared__ float QV[4096];      // 16KB union: Qs (1280 fl) then Vl (4096 fl)
  const int bh = blockIdx.x, sc = blockIdx.y, tid = threadIdx.x;
  const int u0 = blockIdx.z * UG;
  const int s0 = sc * 256;
  const int wid = tid >> 6, lane = tid & 63;

  // stage Q_red rows [u0, u0+20)
  for (int i = tid; i < UG * DH; i += 256) {
    int u = i >> 6, dk = i & 63;
    int row = Mtop[bh * NT + u0 + u];
    QV[i] = Q[((size_t)bh * SEQ + row) * DH + dk];
  }
  // own K row into regs
  const float* Krow = K + ((size_t)bh * SEQ + s0 + tid) * DH;
  float4 kr[16];
#pragma unroll
  for (int g = 0; g < 16; g++) kr[g] = *(const float4*)&Krow[g * 4];
  __syncthreads();

  // scores + exp (Q reads are wave-broadcast)
  for (int u = 0; u < UG; u++) {
    float acc = 0.f;
#pragma unroll
    for (int g = 0; g < 16; g++) {
      float4 qv = *(const float4*)&QV[u * DH + g * 4];
      acc = fmaf(qv.x, kr[g].x, acc);
      acc = fmaf(qv.y, kr[g].y, acc);
      acc = fmaf(qv.z, kr[g].z, acc);
      acc = fmaf(qv.w, kr[g].w, acc);
    }
    El[u * 256 + tid] = __expf(acc * 0.125f);
  }
  __syncthreads();

  // per-u partial denominators (wave wid owns u = wid+4i, i<5)
#pragma unroll
  for (int i = 0; i < 5; i++) {
    const int u = wid + 4 * i;
    float p = El[u * 256 + lane] + El[u * 256 + 64 + lane] +
              El[u * 256 + 128 + lane] + El[u * 256 + 192 + lane];
#pragma unroll
    for (int o = 1; o <= 32; o <<= 1) p += __shfl_xor(p, o, 64);
    if (lane == 0) dpart[(bh * NSC + sc) * NT + u0 + u] = p;
  }

  // PV: acc[u=wid+4i][dk=lane] over 4 sub-steps of 64 rows
  float acc[5] = {};
  for (int st = 0; st < 4; st++) {
    __syncthreads();
#pragma unroll
    for (int i = 0; i < 16; i++) {
      int idx = tid + i * 256;
      int sj = idx >> 6, d2 = idx & 63;
      QV[idx] = V[((size_t)bh * SEQ + s0 + st * 64 + sj) * DH + d2];
    }
    __syncthreads();
    for (int g = 0; g < 16; g++) {
      float a[5][4];
#pragma unroll
      for (int i = 0; i < 5; i++) {
        float4 t = *(const float4*)&El[(wid + 4 * i) * 256 + st * 64 + g * 4];
        a[i][0] = t.x; a[i][1] = t.y; a[i][2] = t.z; a[i][3] = t.w;
      }
#pragma unroll
      for (int t = 0; t < 4; t++) {
        float v = QV[(g * 4 + t) * DH + lane];
#pragma unroll
        for (int i = 0; i < 5; i++) acc[i] = fmaf(a[i][t], v, acc[i]);
      }
    }
  }

#pragma unroll
  for (int i = 0; i < 5; i++) {
    int u = u0 + wid + 4 * i;
    updp[((size_t)(bh * NSC + sc) * NT + u) * DH + lane] = acc[i];
  }
}

// ---------------------------------------------------------------------------
// Combine chunk partials (fixed order), normalize, scatter bf16 into CH.
// ---------------------------------------------------------------------------
__global__ __launch_bounds__(256) void reduce_scatter_kernel(const float* __restrict__ updp,
                                                             const float* __restrict__ dpart,
                                                             const int* __restrict__ Mtop,
                                                             u16* __restrict__ CH) {
  const int bh = blockIdx.x;
  const int u = blockIdx.y * 4 + (threadIdx.x >> 6);
  const int dk = threadIdx.x & 63;
  float s = 0.f, d = 0.f;
#pragma unroll
  for (int sc = 0; sc < NSC; sc++) {
    s += updp[((size_t)(bh * NSC + sc) * NT + u) * DH + dk];
    d += dpart[(bh * NSC + sc) * NT + u];
  }
  const int row = Mtop[bh * NT + u];
  const int b = bh >> 3, h = bh & 7;
  CH[((size_t)b * SEQ + row) * DM + h * DH + dk] = f2bf(s / d);
}

// ---------------------------------------------------------------------------
extern "C" void kernel_launch(void* const* d_in, const int* in_sizes, int n_in,
                              void* d_out, int out_size, void* d_ws, size_t ws_size,
                              hipStream_t stream) {
  (void)in_sizes; (void)n_in; (void)out_size; (void)ws_size;
  const float* queries = (const float*)d_in[0];
  const float* keys    = (const float*)d_in[1];
  const float* values  = (const float*)d_in[2];
  const int* index_sample = (const int*)d_in[4];
  const float* Wq = (const float*)d_in[5];
  const float* bq = (const float*)d_in[6];
  const float* Wk = (const float*)d_in[7];
  const float* bk = (const float*)d_in[8];
  const float* Wv = (const float*)d_in[9];
  const float* bv = (const float*)d_in[10];
  const float* Wo = (const float*)d_in[11];
  const float* bo = (const float*)d_in[12];
  float* out = (float*)d_out;

  // ws layout (floats) — no aliasing.
  float* ws = (float*)d_ws;
  float* Q      = ws;
  float* Kp     = Q + (size_t)ROWS * DM;
  float* Vp     = Kp + (size_t)ROWS * DM;
  float* M      = Vp + (size_t)ROWS * DM;
  float* Vsum   = M + BHROWS;
  float* vpart  = Vsum + NB * NH * DH;
  float* dpart  = vpart + NB * NH * VCH * DH;
  float* updp   = dpart + (size_t)NSC * NB * NH * NT;
  int*   Mtop   = (int*)(updp + (size_t)NSC * NB * NH * NT * DH);
  u16* QXH = (u16*)(Mtop + NB * NH * NT + 64);
  u16* QXL = QXH + (size_t)ROWS * DM;
  u16* KXH = QXL + (size_t)ROWS * DM;
  u16* KXL = KXH + (size_t)ROWS * DM;
  u16* VXH = KXL + (size_t)ROWS * DM;
  u16* CH  = VXH + (size_t)ROWS * DM;
  u16* WqH = CH + (size_t)ROWS * DM;
  u16* WqL = WqH + (size_t)DM * DM;
  u16* WkH = WqL + (size_t)DM * DM;
  u16* WkL = WkH + (size_t)DM * DM;
  u16* WvH = WkL + (size_t)DM * DM;
  u16* WoH = WvH + (size_t)DM * DM;

  const int n4x = ROWS * DM / 4;

  cvt_all<<<dim3(n4x / 256, 1, 4), 256, 0, stream>>>(
      queries, keys, values, Wq, Wk, Wv, Wo,
      QXH, QXL, KXH, KXL, VXH, WqH, WqL, WkH, WkL, WvH, WoH);
  gemm_proj<<<dim3(ROWS / 128, DM / 128, 3), 256, 0, stream>>>(
      QXH, QXL, KXH, KXL, VXH, WqH, WqL, WkH, WkL, WvH, bq, bk, bv, Q, Kp, Vp);

  m_kernel<<<BHROWS / 4, 256, 0, stream>>>(Q, Kp, index_sample, M);
  topk_kernel<<<NB * NH, 1024, 0, stream>>>(M, Mtop);
  vsum1_kernel<<<dim3(NB * NH, VCH), 256, 0, stream>>>(Vp, vpart);
  vsum2_kernel<<<NB * NH, 64, 0, stream>>>(vpart, Vsum);
  ctxinit_kernel<<<(ROWS * DM / 4) / 256, 256, 0, stream>>>(Vsum, CH);
  pv_fused_kernel<<<dim3(NB * NH, NSC, NT / UG), 256, 0, stream>>>(Q, Kp, Vp, Mtop, updp, dpart);
  reduce_scatter_kernel<<<dim3(NB * NH, NT / 4), 256, 0, stream>>>(updp, dpart, Mtop, CH);

  gemm_out<<<dim3(ROWS / 128, DM / 64), 256, 0, stream>>>(CH, WoH, bo, out);
}

// Round 23
// 176.067 us; speedup vs baseline: 1.0019x; 1.0019x over previous
//
#include <hip/hip_runtime.h>

// ProbSparse attention (Informer) — B=4, L=2048, D=512, H=8, DK=64, SK=NTOP=40
// Round 19: gemm_proj K-loop -> double-buffered single-barrier schedule
// (T3 "minimum 2-phase": prefetch next tile BEFORE compute, one
// __syncthreads()/K-step whose implicit vmcnt(0) drains after MFMA covered
// the load latency). LDS 32->64KB (2 blocks/CU). gemm_out unchanged (control).
// Everything else bit-identical to R18.

typedef unsigned short u16;
typedef unsigned long long u64;
typedef __attribute__((ext_vector_type(8))) short short8;
typedef __attribute__((ext_vector_type(4))) float f32x4;

constexpr int NB = 4;       // batch
constexpr int SEQ = 2048;   // L
constexpr int DM = 512;     // D
constexpr int NH = 8;
constexpr int DH = 64;      // DK
constexpr int NS = 40;      // SK (samples)
constexpr int NT = 40;      // NTOP
constexpr int ROWS = NB * SEQ;          // 8192
constexpr int BHROWS = NB * NH * SEQ;   // 65536
constexpr int NSC = 8;      // s-chunks in pv (SEQ/256)
constexpr int VCH = 16;     // vsum l-chunks per (b,h)
constexpr int UG = 20;      // u's per pv block (40/2)

// ---------------------------------------------------------------------------
// bf16 helpers (round-to-nearest-even)
// ---------------------------------------------------------------------------
__device__ __forceinline__ u16 f2bf(float x) {
  union { float f; unsigned u; } v; v.f = x;
  unsigned r = v.u + 0x7FFFu + ((v.u >> 16) & 1u);
  return (u16)(r >> 16);
}
__device__ __forceinline__ float bf2f(u16 b) {
  union { unsigned u; float f; } v; v.u = ((unsigned)b) << 16;
  return v.f;
}

__device__ __forceinline__ void gload16(void* lds, const void* g) {
  __builtin_amdgcn_global_load_lds(
      (const __attribute__((address_space(1))) unsigned int*)g,
      (__attribute__((address_space(3))) unsigned int*)lds, 16, 0, 0);
}

// ---------------------------------------------------------------------------
// Merged conversions. z=0..2: X->bf16 (q hi+lo, k hi+lo, v hi).
// z=3, blockIdx.x<256: W [k][n] fp32 -> [n][k] bf16 (Wq/Wk hi+lo, Wv/Wo hi).
// ---------------------------------------------------------------------------
__global__ __launch_bounds__(256) void cvt_all(const float* __restrict__ q,
                                               const float* __restrict__ k,
                                               const float* __restrict__ v,
                                               const float* __restrict__ Wq,
                                               const float* __restrict__ Wk,
                                               const float* __restrict__ Wv,
                                               const float* __restrict__ Wo,
                                               u16* __restrict__ QXH, u16* __restrict__ QXL,
                                               u16* __restrict__ KXH, u16* __restrict__ KXL,
                                               u16* __restrict__ VXH,
                                               u16* __restrict__ WqH, u16* __restrict__ WqL,
                                               u16* __restrict__ WkH, u16* __restrict__ WkL,
                                               u16* __restrict__ WvH, u16* __restrict__ WoH) {
  __shared__ float T[64][65];
  const int z = blockIdx.z, t = threadIdx.x;
  if (z < 3) {
    const int i = blockIdx.x * 256 + t;
    const float* X = (z == 0) ? q : (z == 1) ? k : v;
    u16* H = (z == 0) ? QXH : (z == 1) ? KXH : VXH;
    u16* L = (z == 0) ? QXL : KXL;
    float4 val = ((const float4*)X)[i];
    ushort4 h;
    h.x = f2bf(val.x); h.y = f2bf(val.y); h.z = f2bf(val.z); h.w = f2bf(val.w);
    ((ushort4*)H)[i] = h;
    if (z < 2) {
      ushort4 l;
      l.x = f2bf(val.x - bf2f(h.x)); l.y = f2bf(val.y - bf2f(h.y));
      l.z = f2bf(val.z - bf2f(h.z)); l.w = f2bf(val.w - bf2f(h.w));
      ((ushort4*)L)[i] = l;
    }
    return;
  }
  if (blockIdx.x >= 256) return;
  const int wz = blockIdx.x >> 6;
  const int c0 = (blockIdx.x & 7) * 64;
  const int r0 = ((blockIdx.x >> 3) & 7) * 64;
  const float* W = (wz == 0) ? Wq : (wz == 1) ? Wk : (wz == 2) ? Wv : Wo;
  u16* H = (wz == 0) ? WqH : (wz == 1) ? WkH : (wz == 2) ? WvH : WoH;
  u16* L = (wz == 0) ? WqL : WkL;
  const int doLo = (wz < 2);
  const int lr = t >> 4, lc4 = (t & 15) * 4;
#pragma unroll
  for (int i = 0; i < 4; i++) {
    float4 val = *(const float4*)&W[(size_t)(r0 + lr + i * 16) * DM + c0 + lc4];
    T[lr + i * 16][lc4 + 0] = val.x;
    T[lr + i * 16][lc4 + 1] = val.y;
    T[lr + i * 16][lc4 + 2] = val.z;
    T[lr + i * 16][lc4 + 3] = val.w;
  }
  __syncthreads();
#pragma unroll
  for (int i = 0; i < 4; i++) {
    const int n = lr + i * 16;
    float x0 = T[lc4 + 0][n], x1 = T[lc4 + 1][n], x2 = T[lc4 + 2][n], x3 = T[lc4 + 3][n];
    ushort4 h;
    h.x = f2bf(x0); h.y = f2bf(x1); h.z = f2bf(x2); h.w = f2bf(x3);
    *(ushort4*)&H[(size_t)(c0 + n) * DM + r0 + lc4] = h;
    if (doLo) {
      ushort4 l;
      l.x = f2bf(x0 - bf2f(h.x)); l.y = f2bf(x1 - bf2f(h.y));
      l.z = f2bf(x2 - bf2f(h.z)); l.w = f2bf(x3 - bf2f(h.w));
      *(ushort4*)&L[(size_t)(c0 + n) * DM + r0 + lc4] = l;
    }
  }
}

// ---------------------------------------------------------------------------
// 128x128 GEMM body, DOUBLE-BUFFERED single-barrier K-loop (T3 minimum):
// prologue stage -> barrier -> { prefetch(next) ; ds_read+MFMA(cur) ;
// barrier } x16. LDS arrays are 2x sized; buf select via +cur*BUF.
// ---------------------------------------------------------------------------
template <bool SPLIT3, bool TOSPLIT>
__device__ __forceinline__ void gemm_body128(const u16* __restrict__ XH,
                                             const u16* __restrict__ XL,
                                             const u16* __restrict__ WTH,
                                             const u16* __restrict__ WTL,
                                             const float* __restrict__ bias,
                                             float* __restrict__ out,
                                             u16* Ah, u16* Al, u16* Bh, u16* Bl,
                                             int row0, int col0) {
  const int tid = threadIdx.x, lane = tid & 63, w = tid >> 6;
  const int wr = (w >> 1) * 64, wc = (w & 1) * 64;
  const int lr = lane & 15, kb8 = (lane >> 4) * 8;
  const int mrow = lane >> 2;
  const int kcol = (lane & 3) * 8;
  constexpr int PER = SPLIT3 ? 8 : 4;
  constexpr int BUF = 128 * 32;

  f32x4 acc[4][4];
#pragma unroll
  for (int i = 0; i < 4; i++)
#pragma unroll
    for (int j = 0; j < 4; j++) acc[i][j] = (f32x4){0.f, 0.f, 0.f, 0.f};

  auto stage = [&](int buf, int k0) {
#pragma unroll
    for (int i = 0; i < PER; i++) {
      const int c = w * PER + i;
      const u16* g;
      u16* l;
      if (SPLIT3) {
        if (c < 8)       { g = XH  + (size_t)(row0 + c * 16 + mrow) * DM + k0 + kcol;        l = Ah + buf * BUF + c * 512; }
        else if (c < 16) { g = XL  + (size_t)(row0 + (c - 8) * 16 + mrow) * DM + k0 + kcol;  l = Al + buf * BUF + (c - 8) * 512; }
        else if (c < 24) { g = WTH + (size_t)(col0 + (c - 16) * 16 + mrow) * DM + k0 + kcol; l = Bh + buf * BUF + (c - 16) * 512; }
        else             { g = WTL + (size_t)(col0 + (c - 24) * 16 + mrow) * DM + k0 + kcol; l = Bl + buf * BUF + (c - 24) * 512; }
      } else {
        if (c < 8)       { g = XH  + (size_t)(row0 + c * 16 + mrow) * DM + k0 + kcol;        l = Ah + buf * BUF + c * 512; }
        else             { g = WTH + (size_t)(col0 + (c - 8) * 16 + mrow) * DM + k0 + kcol;  l = Bh + buf * BUF + (c - 8) * 512; }
      }
      gload16(l, g);
    }
  };

  stage(0, 0);
  __syncthreads();   // drains prologue loads (implicit vmcnt(0))

  int cur = 0;
  for (int k0 = 0; k0 < DM; k0 += 32) {
    if (k0 + 32 < DM) stage(cur ^ 1, k0 + 32);   // prefetch next tile

    const int ob = cur * BUF;
    short8 ah[4], bh[4];
#pragma unroll
    for (int i = 0; i < 4; i++) ah[i] = *(const short8*)&Ah[ob + (wr + i * 16 + lr) * 32 + kb8];
#pragma unroll
    for (int j = 0; j < 4; j++) bh[j] = *(const short8*)&Bh[ob + (wc + j * 16 + lr) * 32 + kb8];
    if constexpr (SPLIT3) {
      short8 al[4], bl[4];
#pragma unroll
      for (int i = 0; i < 4; i++) al[i] = *(const short8*)&Al[ob + (wr + i * 16 + lr) * 32 + kb8];
#pragma unroll
      for (int j = 0; j < 4; j++) bl[j] = *(const short8*)&Bl[ob + (wc + j * 16 + lr) * 32 + kb8];
#pragma unroll
      for (int i = 0; i < 4; i++)
#pragma unroll
        for (int j = 0; j < 4; j++) {
          acc[i][j] = __builtin_amdgcn_mfma_f32_16x16x32_bf16(ah[i], bh[j], acc[i][j], 0, 0, 0);
          acc[i][j] = __builtin_amdgcn_mfma_f32_16x16x32_bf16(ah[i], bl[j], acc[i][j], 0, 0, 0);
          acc[i][j] = __builtin_amdgcn_mfma_f32_16x16x32_bf16(al[i], bh[j], acc[i][j], 0, 0, 0);
        }
    } else {
#pragma unroll
      for (int i = 0; i < 4; i++)
#pragma unroll
        for (int j = 0; j < 4; j++)
          acc[i][j] = __builtin_amdgcn_mfma_f32_16x16x32_bf16(ah[i], bh[j], acc[i][j], 0, 0, 0);
    }

    __syncthreads();   // joins waves + drains prefetch (vmcnt(0))
    cur ^= 1;
  }

#pragma unroll
  for (int i = 0; i < 4; i++)
#pragma unroll
    for (int j = 0; j < 4; j++) {
      const int col = col0 + wc + j * 16 + lr;
      const float bval = bias[col];
#pragma unroll
      for (int r = 0; r < 4; r++) {
        const int row = row0 + wr + i * 16 + (lane >> 4) * 4 + r;
        const float v = acc[i][j][r] + bval;
        if constexpr (TOSPLIT) {
          const int b = row >> 11, l2 = row & (SEQ - 1);
          const int h = col >> 6, dk = col & 63;
          out[((size_t)(b * NH + h) * SEQ + l2) * DH + dk] = v;
        } else {
          out[(size_t)row * DM + col] = v;
        }
      }
    }
}

// ---------------------------------------------------------------------------
// 128x64 GEMM body (unchanged 2-barrier structure; control).
// ---------------------------------------------------------------------------
template <bool SPLIT3, bool TOSPLIT>
__device__ __forceinline__ void gemm_body64(const u16* __restrict__ XH,
                                            const u16* __restrict__ XL,
                                            const u16* __restrict__ WTH,
                                            const u16* __restrict__ WTL,
                                            const float* __restrict__ bias,
                                            float* __restrict__ out,
                                            u16* Ah, u16* Al, u16* Bh, u16* Bl,
                                            int row0, int col0) {
  const int tid = threadIdx.x, lane = tid & 63, w = tid >> 6;
  const int wr = (w >> 1) * 64, wc = (w & 1) * 32;
  const int lr = lane & 15, kb8 = (lane >> 4) * 8;
  const int mrow = lane >> 2;
  const int kcol = (lane & 3) * 8;

  f32x4 acc[4][2];
#pragma unroll
  for (int i = 0; i < 4; i++)
#pragma unroll
    for (int j = 0; j < 2; j++) acc[i][j] = (f32x4){0.f, 0.f, 0.f, 0.f};

  constexpr int PER = SPLIT3 ? 6 : 3;

  for (int k0 = 0; k0 < DM; k0 += 32) {
    __syncthreads();
#pragma unroll
    for (int i = 0; i < PER; i++) {
      const int c = w * PER + i;
      const u16* g;
      u16* l;
      if (SPLIT3) {
        if (c < 8)       { g = XH  + (size_t)(row0 + c * 16 + mrow) * DM + k0 + kcol;        l = Ah + c * 512; }
        else if (c < 16) { g = XL  + (size_t)(row0 + (c - 8) * 16 + mrow) * DM + k0 + kcol;  l = Al + (c - 8) * 512; }
        else if (c < 20) { g = WTH + (size_t)(col0 + (c - 16) * 16 + mrow) * DM + k0 + kcol; l = Bh + (c - 16) * 512; }
        else             { g = WTL + (size_t)(col0 + (c - 20) * 16 + mrow) * DM + k0 + kcol; l = Bl + (c - 20) * 512; }
      } else {
        if (c < 8)       { g = XH  + (size_t)(row0 + c * 16 + mrow) * DM + k0 + kcol;        l = Ah + c * 512; }
        else             { g = WTH + (size_t)(col0 + (c - 8) * 16 + mrow) * DM + k0 + kcol;  l = Bh + (c - 8) * 512; }
      }
      gload16(l, g);
    }
    __syncthreads();

    short8 ah[4], bh[2];
#pragma unroll
    for (int i = 0; i < 4; i++) ah[i] = *(const short8*)&Ah[(wr + i * 16 + lr) * 32 + kb8];
#pragma unroll
    for (int j = 0; j < 2; j++) bh[j] = *(const short8*)&Bh[(wc + j * 16 + lr) * 32 + kb8];
    if constexpr (SPLIT3) {
      short8 al[4], bl[2];
#pragma unroll
      for (int i = 0; i < 4; i++) al[i] = *(const short8*)&Al[(wr + i * 16 + lr) * 32 + kb8];
#pragma unroll
      for (int j = 0; j < 2; j++) bl[j] = *(const short8*)&Bl[(wc + j * 16 + lr) * 32 + kb8];
#pragma unroll
      for (int i = 0; i < 4; i++)
#pragma unroll
        for (int j = 0; j < 2; j++) {
          acc[i][j] = __builtin_amdgcn_mfma_f32_16x16x32_bf16(ah[i], bh[j], acc[i][j], 0, 0, 0);
          acc[i][j] = __builtin_amdgcn_mfma_f32_16x16x32_bf16(ah[i], bl[j], acc[i][j], 0, 0, 0);
          acc[i][j] = __builtin_amdgcn_mfma_f32_16x16x32_bf16(al[i], bh[j], acc[i][j], 0, 0, 0);
        }
    } else {
#pragma unroll
      for (int i = 0; i < 4; i++)
#pragma unroll
        for (int j = 0; j < 2; j++)
          acc[i][j] = __builtin_amdgcn_mfma_f32_16x16x32_bf16(ah[i], bh[j], acc[i][j], 0, 0, 0);
    }
  }

#pragma unroll
  for (int i = 0; i < 4; i++)
#pragma unroll
    for (int j = 0; j < 2; j++) {
      const int col = col0 + wc + j * 16 + lr;
      const float bval = bias[col];
#pragma unroll
      for (int r = 0; r < 4; r++) {
        const int row = row0 + wr + i * 16 + (lane >> 4) * 4 + r;
        const float v = acc[i][j][r] + bval;
        if constexpr (TOSPLIT) {
          const int b = row >> 11, l2 = row & (SEQ - 1);
          const int h = col >> 6, dk = col & 63;
          out[((size_t)(b * NH + h) * SEQ + l2) * DH + dk] = v;
        } else {
          out[(size_t)row * DM + col] = v;
        }
      }
    }
}

// ---------------------------------------------------------------------------
// Merged projection GEMM (128x128, double-buffered): z=0 Q, z=1 K, z=2 V.
// ---------------------------------------------------------------------------
__global__ __launch_bounds__(256) void gemm_proj(const u16* __restrict__ QXH, const u16* __restrict__ QXL,
                                                 const u16* __restrict__ KXH, const u16* __restrict__ KXL,
                                                 const u16* __restrict__ VXH,
                                                 const u16* __restrict__ WqH, const u16* __restrict__ WqL,
                                                 const u16* __restrict__ WkH, const u16* __restrict__ WkL,
                                                 const u16* __restrict__ WvH,
                                                 const float* __restrict__ bq, const float* __restrict__ bk,
                                                 const float* __restrict__ bv,
                                                 float* __restrict__ Q, float* __restrict__ Kp,
                                                 float* __restrict__ Vp) {
  __shared__ __align__(16) u16 Ah[2 * 128 * 32];
  __shared__ __align__(16) u16 Al[2 * 128 * 32];
  __shared__ __align__(16) u16 Bh[2 * 128 * 32];
  __shared__ __align__(16) u16 Bl[2 * 128 * 32];
  const int row0 = blockIdx.x * 128, col0 = blockIdx.y * 128;
  if (blockIdx.z == 0)
    gemm_body128<true, true>(QXH, QXL, WqH, WqL, bq, Q, Ah, Al, Bh, Bl, row0, col0);
  else if (blockIdx.z == 1)
    gemm_body128<true, true>(KXH, KXL, WkH, WkL, bk, Kp, Ah, Al, Bh, Bl, row0, col0);
  else
    gemm_body128<false, true>(VXH, VXH, WvH, WvH, bv, Vp, Ah, Al, Bh, Bl, row0, col0);
}

// ---------------------------------------------------------------------------
// Output GEMM (128x64): CH bf16 @ WoH + bo -> out.
// ---------------------------------------------------------------------------
__global__ __launch_bounds__(256) void gemm_out(const u16* __restrict__ CH,
                                                const u16* __restrict__ WoH,
                                                const float* __restrict__ bo,
                                                float* __restrict__ out) {
  __shared__ __align__(16) u16 Ah[128 * 32];
  __shared__ __align__(16) u16 Al[128 * 32];
  __shared__ __align__(16) u16 Bh[64 * 32];
  __shared__ __align__(16) u16 Bl[64 * 32];
  gemm_body64<false, false>(CH, CH, WoH, WoH, bo, out, Ah, Al, Bh, Bl,
                            blockIdx.x * 128, blockIdx.y * 64);
}

// ---------------------------------------------------------------------------
// M[b,h,q]. One wave per row; idx via LDS; bijective XCD swizzle for K L2-res.
// ---------------------------------------------------------------------------
__global__ __launch_bounds__(256) void m_kernel(const float* __restrict__ Q,
                                                const float* __restrict__ K,
                                                const int* __restrict__ idxs,
                                                float* __restrict__ M) {
  __shared__ int idl[4 * NS];
  const int tid = threadIdx.x;
  const int x = blockIdx.x & 7;        // XCD
  const int slot = blockIdx.x >> 3;
  const int bh = x * 4 + (slot >> 9);  // 4 bh-slices per XCD
  const int q0 = (slot & 511) * 4;

  if (tid < 4 * NS) idl[tid] = idxs[q0 * NS + tid];
  __syncthreads();

  const int lane = tid & 63, wid = tid >> 6;
  const int r = bh * SEQ + q0 + wid;
  const int g = lane >> 3;
  const int d8 = (lane & 7) * 8;
  const float* Qr = Q + (size_t)r * DH + d8;
  const float4 q0v = *(const float4*)Qr;
  const float4 q1v = *(const float4*)(Qr + 4);
  const float* Kbh = K + (size_t)bh * SEQ * DH;

  int ks[5];
#pragma unroll
  for (int p = 0; p < 5; p++) ks[p] = idl[wid * NS + g + 8 * p];
  float4 k0[5], k1[5];
#pragma unroll
  for (int p = 0; p < 5; p++) {
    const float* Kr = Kbh + (size_t)ks[p] * DH + d8;
    k0[p] = *(const float4*)Kr;
    k1[p] = *(const float4*)(Kr + 4);
  }
  float mx = -1e30f, sm = 0.f;
#pragma unroll
  for (int p = 0; p < 5; p++) {
    float acc = q0v.x * k0[p].x + q0v.y * k0[p].y + q0v.z * k0[p].z + q0v.w * k0[p].w +
                q1v.x * k1[p].x + q1v.y * k1[p].y + q1v.z * k1[p].z + q1v.w * k1[p].w;
    acc += __shfl_xor(acc, 1, 64);
    acc += __shfl_xor(acc, 2, 64);
    acc += __shfl_xor(acc, 4, 64);
    mx = fmaxf(mx, acc);
    sm += acc;
  }
#pragma unroll
  for (int o = 8; o <= 32; o <<= 1) {
    mx = fmaxf(mx, __shfl_xor(mx, o, 64));
    sm += __shfl_xor(sm, o, 64);
  }
  if (lane == 0) M[r] = mx - sm * (1.0f / (float)SEQ);
}

// ---------------------------------------------------------------------------
// Top-40 per (b,h) via bitonic sort of packed u64 keys. 1024 thr per (b,h).
// ---------------------------------------------------------------------------
__global__ __launch_bounds__(1024) void topk_kernel(const float* __restrict__ M,
                                                    int* __restrict__ Mtop) {
  __shared__ u64 keys[SEQ];
  const int bh = blockIdx.x, tid = threadIdx.x;
  const float* Mb = M + (size_t)bh * SEQ;
#pragma unroll
  for (int i = tid; i < SEQ; i += 1024) {
    unsigned ub = __float_as_uint(Mb[i]);
    ub ^= (ub >> 31) ? 0xFFFFFFFFu : 0x80000000u;
    keys[i] = ((u64)ub << 32) | (u64)(unsigned)~i;
  }
  __syncthreads();
  for (int k = 2; k <= SEQ; k <<= 1) {
    for (int j = k >> 1; j > 0; j >>= 1) {
#pragma unroll
      for (int i = tid; i < SEQ; i += 1024) {
        const int partner = i ^ j;
        if (partner > i) {
          const u64 a = keys[i], b = keys[partner];
          const bool desc = ((i & k) == 0);
          if (desc ? (a < b) : (a > b)) { keys[i] = b; keys[partner] = a; }
        }
      }
      __syncthreads();
    }
  }
  if (tid < NT) Mtop[bh * NT + tid] = (int)~(unsigned)keys[tid];
}

// ---------------------------------------------------------------------------
// V_sum two-stage.
// ---------------------------------------------------------------------------
__global__ __launch_bounds__(256) void vsum1_kernel(const float* __restrict__ V,
                                                    float* __restrict__ part) {
  __shared__ float sm[4][DH];
  const int bh = blockIdx.x, c = blockIdx.y, tid = threadIdx.x;
  const int dk = tid & 63, p = tid >> 6;
  const float* Vb = V + ((size_t)bh * SEQ + c * (SEQ / VCH)) * DH;
  float s = 0.f;
  for (int l = p; l < SEQ / VCH; l += 4) s += Vb[(size_t)l * DH + dk];
  sm[p][dk] = s;
  __syncthreads();
  if (p == 0)
    part[(size_t)(bh * VCH + c) * DH + dk] = sm[0][dk] + sm[1][dk] + sm[2][dk] + sm[3][dk];
}

__global__ __launch_bounds__(64) void vsum2_kernel(const float* __restrict__ part,
                                                   float* __restrict__ Vsum) {
  const int bh = blockIdx.x, dk = threadIdx.x;
  float s = 0.f;
#pragma unroll
  for (int c = 0; c < VCH; c++) s += part[(size_t)(bh * VCH + c) * DH + dk];
  Vsum[bh * DH + dk] = s;
}

// ---------------------------------------------------------------------------
// CH (B,L,D) bf16: V_sum broadcast (selected rows overwritten later).
// ---------------------------------------------------------------------------
__global__ __launch_bounds__(256) void ctxinit_kernel(const float* __restrict__ Vsum,
                                                      u16* __restrict__ CH) {
  const int idx = blockIdx.x * 256 + threadIdx.x;
  const int f = idx * 4;
  const int d = f & (DM - 1), b = f >> 20;
  float4 v = *(const float4*)&Vsum[b * DM + d];
  ushort4 h;
  h.x = f2bf(v.x); h.y = f2bf(v.y); h.z = f2bf(v.z); h.w = f2bf(v.w);
  ((ushort4*)CH)[idx] = h;
}

// ---------------------------------------------------------------------------
// Fused scores+softmax-partial+PV. Block (bh, sc, ug): 256 s-rows, 20 u's.
// Unnormalized: El = exp(Q_red·K/8); dpart = per-u row-sums; updp = El@V.
// ---------------------------------------------------------------------------
__global__ __launch_bounds__(256) void pv_fused_kernel(const float* __restrict__ Q,
                                                       const float* __restrict__ K,
                                                       const float* __restrict__ V,
                                                       const int* __restrict__ Mtop,
                                                       float* __restrict__ updp,
                                                       float* __restrict__ dpart) {
  __shared__ float El[UG * 256];  // 20KB: exp'd scores [u_local][sj]
  __shared__ float QV[4096];      // 16KB union: Qs (1280 fl) then Vl (4096 fl)
  const int bh = blockIdx.x, sc = blockIdx.y, tid = threadIdx.x;
  const int u0 = blockIdx.z * UG;
  const int s0 = sc * 256;
  const int wid = tid >> 6, lane = tid & 63;

  // stage Q_red rows [u0, u0+20)
  for (int i = tid; i < UG * DH; i += 256) {
    int u = i >> 6, dk = i & 63;
    int row = Mtop[bh * NT + u0 + u];
    QV[i] = Q[((size_t)bh * SEQ + row) * DH + dk];
  }
  // own K row into regs
  const float* Krow = K + ((size_t)bh * SEQ + s0 + tid) * DH;
  float4 kr[16];
#pragma unroll
  for (int g = 0; g < 16; g++) kr[g] = *(const float4*)&Krow[g * 4];
  __syncthreads();

  // scores + exp (Q reads are wave-broadcast)
  for (int u = 0; u < UG; u++) {
    float acc = 0.f;
#pragma unroll
    for (int g = 0; g < 16; g++) {
      float4 qv = *(const float4*)&QV[u * DH + g * 4];
      acc = fmaf(qv.x, kr[g].x, acc);
      acc = fmaf(qv.y, kr[g].y, acc);
      acc = fmaf(qv.z, kr[g].z, acc);
      acc = fmaf(qv.w, kr[g].w, acc);
    }
    El[u * 256 + tid] = __expf(acc * 0.125f);
  }
  __syncthreads();

  // per-u partial denominators (wave wid owns u = wid+4i, i<5)
#pragma unroll
  for (int i = 0; i < 5; i++) {
    const int u = wid + 4 * i;
    float p = El[u * 256 + lane] + El[u * 256 + 64 + lane] +
              El[u * 256 + 128 + lane] + El[u * 256 + 192 + lane];
#pragma unroll
    for (int o = 1; o <= 32; o <<= 1) p += __shfl_xor(p, o, 64);
    if (lane == 0) dpart[(bh * NSC + sc) * NT + u0 + u] = p;
  }

  // PV: acc[u=wid+4i][dk=lane] over 4 sub-steps of 64 rows
  float acc[5] = {};
  for (int st = 0; st < 4; st++) {
    __syncthreads();
#pragma unroll
    for (int i = 0; i < 16; i++) {
      int idx = tid + i * 256;
      int sj = idx >> 6, d2 = idx & 63;
      QV[idx] = V[((size_t)bh * SEQ + s0 + st * 64 + sj) * DH + d2];
    }
    __syncthreads();
    for (int g = 0; g < 16; g++) {
      float a[5][4];
#pragma unroll
      for (int i = 0; i < 5; i++) {
        float4 t = *(const float4*)&El[(wid + 4 * i) * 256 + st * 64 + g * 4];
        a[i][0] = t.x; a[i][1] = t.y; a[i][2] = t.z; a[i][3] = t.w;
      }
#pragma unroll
      for (int t = 0; t < 4; t++) {
        float v = QV[(g * 4 + t) * DH + lane];
#pragma unroll
        for (int i = 0; i < 5; i++) acc[i] = fmaf(a[i][t], v, acc[i]);
      }
    }
  }

#pragma unroll
  for (int i = 0; i < 5; i++) {
    int u = u0 + wid + 4 * i;
    updp[((size_t)(bh * NSC + sc) * NT + u) * DH + lane] = acc[i];
  }
}

// ---------------------------------------------------------------------------
// Combine chunk partials (fixed order), normalize, scatter bf16 into CH.
// ---------------------------------------------------------------------------
__global__ __launch_bounds__(256) void reduce_scatter_kernel(const float* __restrict__ updp,
                                                             const float* __restrict__ dpart,
                                                             const int* __restrict__ Mtop,
                                                             u16* __restrict__ CH) {
  const int bh = blockIdx.x;
  const int u = blockIdx.y * 4 + (threadIdx.x >> 6);
  const int dk = threadIdx.x & 63;
  float s = 0.f, d = 0.f;
#pragma unroll
  for (int sc = 0; sc < NSC; sc++) {
    s += updp[((size_t)(bh * NSC + sc) * NT + u) * DH + dk];
    d += dpart[(bh * NSC + sc) * NT + u];
  }
  const int row = Mtop[bh * NT + u];
  const int b = bh >> 3, h = bh & 7;
  CH[((size_t)b * SEQ + row) * DM + h * DH + dk] = f2bf(s / d);
}

// ---------------------------------------------------------------------------
extern "C" void kernel_launch(void* const* d_in, const int* in_sizes, int n_in,
                              void* d_out, int out_size, void* d_ws, size_t ws_size,
                              hipStream_t stream) {
  (void)in_sizes; (void)n_in; (void)out_size; (void)ws_size;
  const float* queries = (const float*)d_in[0];
  const float* keys    = (const float*)d_in[1];
  const float* values  = (const float*)d_in[2];
  const int* index_sample = (const int*)d_in[4];
  const float* Wq = (const float*)d_in[5];
  const float* bq = (const float*)d_in[6];
  const float* Wk = (const float*)d_in[7];
  const float* bk = (const float*)d_in[8];
  const float* Wv = (const float*)d_in[9];
  const float* bv = (const float*)d_in[10];
  const float* Wo = (const float*)d_in[11];
  const float* bo = (const float*)d_in[12];
  float* out = (float*)d_out;

  // ws layout (floats) — no aliasing.
  float* ws = (float*)d_ws;
  float* Q      = ws;
  float* Kp     = Q + (size_t)ROWS * DM;
  float* Vp     = Kp + (size_t)ROWS * DM;
  float* M      = Vp + (size_t)ROWS * DM;
  float* Vsum   = M + BHROWS;
  float* vpart  = Vsum + NB * NH * DH;
  float* dpart  = vpart + NB * NH * VCH * DH;
  float* updp   = dpart + (size_t)NSC * NB * NH * NT;
  int*   Mtop   = (int*)(updp + (size_t)NSC * NB * NH * NT * DH);
  u16* QXH = (u16*)(Mtop + NB * NH * NT + 64);
  u16* QXL = QXH + (size_t)ROWS * DM;
  u16* KXH = QXL + (size_t)ROWS * DM;
  u16* KXL = KXH + (size_t)ROWS * DM;
  u16* VXH = KXL + (size_t)ROWS * DM;
  u16* CH  = VXH + (size_t)ROWS * DM;
  u16* WqH = CH + (size_t)ROWS * DM;
  u16* WqL = WqH + (size_t)DM * DM;
  u16* WkH = WqL + (size_t)DM * DM;
  u16* WkL = WkH + (size_t)DM * DM;
  u16* WvH = WkL + (size_t)DM * DM;
  u16* WoH = WvH + (size_t)DM * DM;

  const int n4x = ROWS * DM / 4;

  cvt_all<<<dim3(n4x / 256, 1, 4), 256, 0, stream>>>(
      queries, keys, values, Wq, Wk, Wv, Wo,
      QXH, QXL, KXH, KXL, VXH, WqH, WqL, WkH, WkL, WvH, WoH);
  gemm_proj<<<dim3(ROWS / 128, DM / 128, 3), 256, 0, stream>>>(
      QXH, QXL, KXH, KXL, VXH, WqH, WqL, WkH, WkL, WvH, bq, bk, bv, Q, Kp, Vp);

  m_kernel<<<BHROWS / 4, 256, 0, stream>>>(Q, Kp, index_sample, M);
  topk_kernel<<<NB * NH, 1024, 0, stream>>>(M, Mtop);
  vsum1_kernel<<<dim3(NB * NH, VCH), 256, 0, stream>>>(Vp, vpart);
  vsum2_kernel<<<NB * NH, 64, 0, stream>>>(vpart, Vsum);
  ctxinit_kernel<<<(ROWS * DM / 4) / 256, 256, 0, stream>>>(Vsum, CH);
  pv_fused_kernel<<<dim3(NB * NH, NSC, NT / UG), 256, 0, stream>>>(Q, Kp, Vp, Mtop, updp, dpart);
  reduce_scatter_kernel<<<dim3(NB * NH, NT / 4), 256, 0, stream>>>(updp, dpart, Mtop, CH);

  gemm_out<<<dim3(ROWS / 128, DM / 64), 256, 0, stream>>>(CH, WoH, bo, out);
}

// Round 24
// 176.027 us; speedup vs baseline: 1.0021x; 1.0002x over previous
//
#include <hip/hip_runtime.h>

// ProbSparse attention (Informer) — B=4, L=2048, D=512, H=8, DK=64, SK=NTOP=40
// Round 19: gemm_proj K-loop -> double-buffered single-barrier schedule
// (T3 "minimum 2-phase": prefetch next tile BEFORE compute, one
// __syncthreads()/K-step whose implicit vmcnt(0) drains after MFMA covered
// the load latency). LDS 32->64KB (2 blocks/CU). gemm_out unchanged (control).
// Everything else bit-identical to R18.

typedef unsigned short u16;
typedef unsigned long long u64;
typedef __attribute__((ext_vector_type(8))) short short8;
typedef __attribute__((ext_vector_type(4))) float f32x4;

constexpr int NB = 4;       // batch
constexpr int SEQ = 2048;   // L
constexpr int DM = 512;     // D
constexpr int NH = 8;
constexpr int DH = 64;      // DK
constexpr int NS = 40;      // SK (samples)
constexpr int NT = 40;      // NTOP
constexpr int ROWS = NB * SEQ;          // 8192
constexpr int BHROWS = NB * NH * SEQ;   // 65536
constexpr int NSC = 8;      // s-chunks in pv (SEQ/256)
constexpr int VCH = 16;     // vsum l-chunks per (b,h)
constexpr int UG = 20;      // u's per pv block (40/2)

// ---------------------------------------------------------------------------
// bf16 helpers (round-to-nearest-even)
// ---------------------------------------------------------------------------
__device__ __forceinline__ u16 f2bf(float x) {
  union { float f; unsigned u; } v; v.f = x;
  unsigned r = v.u + 0x7FFFu + ((v.u >> 16) & 1u);
  return (u16)(r >> 16);
}
__device__ __forceinline__ float bf2f(u16 b) {
  union { unsigned u; float f; } v; v.u = ((unsigned)b) << 16;
  return v.f;
}

__device__ __forceinline__ void gload16(void* lds, const void* g) {
  __builtin_amdgcn_global_load_lds(
      (const __attribute__((address_space(1))) unsigned int*)g,
      (__attribute__((address_space(3))) unsigned int*)lds, 16, 0, 0);
}

// ---------------------------------------------------------------------------
// Merged conversions. z=0..2: X->bf16 (q hi+lo, k hi+lo, v hi).
// z=3, blockIdx.x<256: W [k][n] fp32 -> [n][k] bf16 (Wq/Wk hi+lo, Wv/Wo hi).
// ---------------------------------------------------------------------------
__global__ __launch_bounds__(256) void cvt_all(const float* __restrict__ q,
                                               const float* __restrict__ k,
                                               const float* __restrict__ v,
                                               const float* __restrict__ Wq,
                                               const float* __restrict__ Wk,
                                               const float* __restrict__ Wv,
                                               const float* __restrict__ Wo,
                                               u16* __restrict__ QXH, u16* __restrict__ QXL,
                                               u16* __restrict__ KXH, u16* __restrict__ KXL,
                                               u16* __restrict__ VXH,
                                               u16* __restrict__ WqH, u16* __restrict__ WqL,
                                               u16* __restrict__ WkH, u16* __restrict__ WkL,
                                               u16* __restrict__ WvH, u16* __restrict__ WoH) {
  __shared__ float T[64][65];
  const int z = blockIdx.z, t = threadIdx.x;
  if (z < 3) {
    const int i = blockIdx.x * 256 + t;
    const float* X = (z == 0) ? q : (z == 1) ? k : v;
    u16* H = (z == 0) ? QXH : (z == 1) ? KXH : VXH;
    u16* L = (z == 0) ? QXL : KXL;
    float4 val = ((const float4*)X)[i];
    ushort4 h;
    h.x = f2bf(val.x); h.y = f2bf(val.y); h.z = f2bf(val.z); h.w = f2bf(val.w);
    ((ushort4*)H)[i] = h;
    if (z < 2) {
      ushort4 l;
      l.x = f2bf(val.x - bf2f(h.x)); l.y = f2bf(val.y - bf2f(h.y));
      l.z = f2bf(val.z - bf2f(h.z)); l.w = f2bf(val.w - bf2f(h.w));
      ((ushort4*)L)[i] = l;
    }
    return;
  }
  if (blockIdx.x >= 256) return;
  const int wz = blockIdx.x >> 6;
  const int c0 = (blockIdx.x & 7) * 64;
  const int r0 = ((blockIdx.x >> 3) & 7) * 64;
  const float* W = (wz == 0) ? Wq : (wz == 1) ? Wk : (wz == 2) ? Wv : Wo;
  u16* H = (wz == 0) ? WqH : (wz == 1) ? WkH : (wz == 2) ? WvH : WoH;
  u16* L = (wz == 0) ? WqL : WkL;
  const int doLo = (wz < 2);
  const int lr = t >> 4, lc4 = (t & 15) * 4;
#pragma unroll
  for (int i = 0; i < 4; i++) {
    float4 val = *(const float4*)&W[(size_t)(r0 + lr + i * 16) * DM + c0 + lc4];
    T[lr + i * 16][lc4 + 0] = val.x;
    T[lr + i * 16][lc4 + 1] = val.y;
    T[lr + i * 16][lc4 + 2] = val.z;
    T[lr + i * 16][lc4 + 3] = val.w;
  }
  __syncthreads();
#pragma unroll
  for (int i = 0; i < 4; i++) {
    const int n = lr + i * 16;
    float x0 = T[lc4 + 0][n], x1 = T[lc4 + 1][n], x2 = T[lc4 + 2][n], x3 = T[lc4 + 3][n];
    ushort4 h;
    h.x = f2bf(x0); h.y = f2bf(x1); h.z = f2bf(x2); h.w = f2bf(x3);
    *(ushort4*)&H[(size_t)(c0 + n) * DM + r0 + lc4] = h;
    if (doLo) {
      ushort4 l;
      l.x = f2bf(x0 - bf2f(h.x)); l.y = f2bf(x1 - bf2f(h.y));
      l.z = f2bf(x2 - bf2f(h.z)); l.w = f2bf(x3 - bf2f(h.w));
      *(ushort4*)&L[(size_t)(c0 + n) * DM + r0 + lc4] = l;
    }
  }
}

// ---------------------------------------------------------------------------
// 128x128 GEMM body, DOUBLE-BUFFERED single-barrier K-loop (T3 minimum):
// prologue stage -> barrier -> { prefetch(next) ; ds_read+MFMA(cur) ;
// barrier } x16. LDS arrays are 2x sized; buf select via +cur*BUF.
// ---------------------------------------------------------------------------
template <bool SPLIT3, bool TOSPLIT>
__device__ __forceinline__ void gemm_body128(const u16* __restrict__ XH,
                                             const u16* __restrict__ XL,
                                             const u16* __restrict__ WTH,
                                             const u16* __restrict__ WTL,
                                             const float* __restrict__ bias,
                                             float* __restrict__ out,
                                             u16* Ah, u16* Al, u16* Bh, u16* Bl,
                                             int row0, int col0) {
  const int tid = threadIdx.x, lane = tid & 63, w = tid >> 6;
  const int wr = (w >> 1) * 64, wc = (w & 1) * 64;
  const int lr = lane & 15, kb8 = (lane >> 4) * 8;
  const int mrow = lane >> 2;
  const int kcol = (lane & 3) * 8;
  constexpr int PER = SPLIT3 ? 8 : 4;
  constexpr int BUF = 128 * 32;

  f32x4 acc[4][4];
#pragma unroll
  for (int i = 0; i < 4; i++)
#pragma unroll
    for (int j = 0; j < 4; j++) acc[i][j] = (f32x4){0.f, 0.f, 0.f, 0.f};

  auto stage = [&](int buf, int k0) {
#pragma unroll
    for (int i = 0; i < PER; i++) {
      const int c = w * PER + i;
      const u16* g;
      u16* l;
      if (SPLIT3) {
        if (c < 8)       { g = XH  + (size_t)(row0 + c * 16 + mrow) * DM + k0 + kcol;        l = Ah + buf * BUF + c * 512; }
        else if (c < 16) { g = XL  + (size_t)(row0 + (c - 8) * 16 + mrow) * DM + k0 + kcol;  l = Al + buf * BUF + (c - 8) * 512; }
        else if (c < 24) { g = WTH + (size_t)(col0 + (c - 16) * 16 + mrow) * DM + k0 + kcol; l = Bh + buf * BUF + (c - 16) * 512; }
        else             { g = WTL + (size_t)(col0 + (c - 24) * 16 + mrow) * DM + k0 + kcol; l = Bl + buf * BUF + (c - 24) * 512; }
      } else {
        if (c < 8)       { g = XH  + (size_t)(row0 + c * 16 + mrow) * DM + k0 + kcol;        l = Ah + buf * BUF + c * 512; }
        else             { g = WTH + (size_t)(col0 + (c - 8) * 16 + mrow) * DM + k0 + kcol;  l = Bh + buf * BUF + (c - 8) * 512; }
      }
      gload16(l, g);
    }
  };

  stage(0, 0);
  __syncthreads();   // drains prologue loads (implicit vmcnt(0))

  int cur = 0;
  for (int k0 = 0; k0 < DM; k0 += 32) {
    if (k0 + 32 < DM) stage(cur ^ 1, k0 + 32);   // prefetch next tile

    const int ob = cur * BUF;
    short8 ah[4], bh[4];
#pragma unroll
    for (int i = 0; i < 4; i++) ah[i] = *(const short8*)&Ah[ob + (wr + i * 16 + lr) * 32 + kb8];
#pragma unroll
    for (int j = 0; j < 4; j++) bh[j] = *(const short8*)&Bh[ob + (wc + j * 16 + lr) * 32 + kb8];
    if constexpr (SPLIT3) {
      short8 al[4], bl[4];
#pragma unroll
      for (int i = 0; i < 4; i++) al[i] = *(const short8*)&Al[ob + (wr + i * 16 + lr) * 32 + kb8];
#pragma unroll
      for (int j = 0; j < 4; j++) bl[j] = *(const short8*)&Bl[ob + (wc + j * 16 + lr) * 32 + kb8];
#pragma unroll
      for (int i = 0; i < 4; i++)
#pragma unroll
        for (int j = 0; j < 4; j++) {
          acc[i][j] = __builtin_amdgcn_mfma_f32_16x16x32_bf16(ah[i], bh[j], acc[i][j], 0, 0, 0);
          acc[i][j] = __builtin_amdgcn_mfma_f32_16x16x32_bf16(ah[i], bl[j], acc[i][j], 0, 0, 0);
          acc[i][j] = __builtin_amdgcn_mfma_f32_16x16x32_bf16(al[i], bh[j], acc[i][j], 0, 0, 0);
        }
    } else {
#pragma unroll
      for (int i = 0; i < 4; i++)
#pragma unroll
        for (int j = 0; j < 4; j++)
          acc[i][j] = __builtin_amdgcn_mfma_f32_16x16x32_bf16(ah[i], bh[j], acc[i][j], 0, 0, 0);
    }

    __syncthreads();   // joins waves + drains prefetch (vmcnt(0))
    cur ^= 1;
  }

#pragma unroll
  for (int i = 0; i < 4; i++)
#pragma unroll
    for (int j = 0; j < 4; j++) {
      const int col = col0 + wc + j * 16 + lr;
      const float bval = bias[col];
#pragma unroll
      for (int r = 0; r < 4; r++) {
        const int row = row0 + wr + i * 16 + (lane >> 4) * 4 + r;
        const float v = acc[i][j][r] + bval;
        if constexpr (TOSPLIT) {
          const int b = row >> 11, l2 = row & (SEQ - 1);
          const int h = col >> 6, dk = col & 63;
          out[((size_t)(b * NH + h) * SEQ + l2) * DH + dk] = v;
        } else {
          out[(size_t)row * DM + col] = v;
        }
      }
    }
}

// ---------------------------------------------------------------------------
// 128x64 GEMM body (unchanged 2-barrier structure; control).
// ---------------------------------------------------------------------------
template <bool SPLIT3, bool TOSPLIT>
__device__ __forceinline__ void gemm_body64(const u16* __restrict__ XH,
                                            const u16* __restrict__ XL,
                                            const u16* __restrict__ WTH,
                                            const u16* __restrict__ WTL,
                                            const float* __restrict__ bias,
                                            float* __restrict__ out,
                                            u16* Ah, u16* Al, u16* Bh, u16* Bl,
                                            int row0, int col0) {
  const int tid = threadIdx.x, lane = tid & 63, w = tid >> 6;
  const int wr = (w >> 1) * 64, wc = (w & 1) * 32;
  const int lr = lane & 15, kb8 = (lane >> 4) * 8;
  const int mrow = lane >> 2;
  const int kcol = (lane & 3) * 8;

  f32x4 acc[4][2];
#pragma unroll
  for (int i = 0; i < 4; i++)
#pragma unroll
    for (int j = 0; j < 2; j++) acc[i][j] = (f32x4){0.f, 0.f, 0.f, 0.f};

  constexpr int PER = SPLIT3 ? 6 : 3;

  for (int k0 = 0; k0 < DM; k0 += 32) {
    __syncthreads();
#pragma unroll
    for (int i = 0; i < PER; i++) {
      const int c = w * PER + i;
      const u16* g;
      u16* l;
      if (SPLIT3) {
        if (c < 8)       { g = XH  + (size_t)(row0 + c * 16 + mrow) * DM + k0 + kcol;        l = Ah + c * 512; }
        else if (c < 16) { g = XL  + (size_t)(row0 + (c - 8) * 16 + mrow) * DM + k0 + kcol;  l = Al + (c - 8) * 512; }
        else if (c < 20) { g = WTH + (size_t)(col0 + (c - 16) * 16 + mrow) * DM + k0 + kcol; l = Bh + (c - 16) * 512; }
        else             { g = WTL + (size_t)(col0 + (c - 20) * 16 + mrow) * DM + k0 + kcol; l = Bl + (c - 20) * 512; }
      } else {
        if (c < 8)       { g = XH  + (size_t)(row0 + c * 16 + mrow) * DM + k0 + kcol;        l = Ah + c * 512; }
        else             { g = WTH + (size_t)(col0 + (c - 8) * 16 + mrow) * DM + k0 + kcol;  l = Bh + (c - 8) * 512; }
      }
      gload16(l, g);
    }
    __syncthreads();

    short8 ah[4], bh[2];
#pragma unroll
    for (int i = 0; i < 4; i++) ah[i] = *(const short8*)&Ah[(wr + i * 16 + lr) * 32 + kb8];
#pragma unroll
    for (int j = 0; j < 2; j++) bh[j] = *(const short8*)&Bh[(wc + j * 16 + lr) * 32 + kb8];
    if constexpr (SPLIT3) {
      short8 al[4], bl[2];
#pragma unroll
      for (int i = 0; i < 4; i++) al[i] = *(const short8*)&Al[(wr + i * 16 + lr) * 32 + kb8];
#pragma unroll
      for (int j = 0; j < 2; j++) bl[j] = *(const short8*)&Bl[(wc + j * 16 + lr) * 32 + kb8];
#pragma unroll
      for (int i = 0; i < 4; i++)
#pragma unroll
        for (int j = 0; j < 2; j++) {
          acc[i][j] = __builtin_amdgcn_mfma_f32_16x16x32_bf16(ah[i], bh[j], acc[i][j], 0, 0, 0);
          acc[i][j] = __builtin_amdgcn_mfma_f32_16x16x32_bf16(ah[i], bl[j], acc[i][j], 0, 0, 0);
          acc[i][j] = __builtin_amdgcn_mfma_f32_16x16x32_bf16(al[i], bh[j], acc[i][j], 0, 0, 0);
        }
    } else {
#pragma unroll
      for (int i = 0; i < 4; i++)
#pragma unroll
        for (int j = 0; j < 2; j++)
          acc[i][j] = __builtin_amdgcn_mfma_f32_16x16x32_bf16(ah[i], bh[j], acc[i][j], 0, 0, 0);
    }
  }

#pragma unroll
  for (int i = 0; i < 4; i++)
#pragma unroll
    for (int j = 0; j < 2; j++) {
      const int col = col0 + wc + j * 16 + lr;
      const float bval = bias[col];
#pragma unroll
      for (int r = 0; r < 4; r++) {
        const int row = row0 + wr + i * 16 + (lane >> 4) * 4 + r;
        const float v = acc[i][j][r] + bval;
        if constexpr (TOSPLIT) {
          const int b = row >> 11, l2 = row & (SEQ - 1);
          const int h = col >> 6, dk = col & 63;
          out[((size_t)(b * NH + h) * SEQ + l2) * DH + dk] = v;
        } else {
          out[(size_t)row * DM + col] = v;
        }
      }
    }
}

// ---------------------------------------------------------------------------
// Merged projection GEMM (128x128, double-buffered): z=0 Q, z=1 K, z=2 V.
// ---------------------------------------------------------------------------
__global__ __launch_bounds__(256) void gemm_proj(const u16* __restrict__ QXH, const u16* __restrict__ QXL,
                                                 const u16* __restrict__ KXH, const u16* __restrict__ KXL,
                                                 const u16* __restrict__ VXH,
                                                 const u16* __restrict__ WqH, const u16* __restrict__ WqL,
                                                 const u16* __restrict__ WkH, const u16* __restrict__ WkL,
                                                 const u16* __restrict__ WvH,
                                                 const float* __restrict__ bq, const float* __restrict__ bk,
                                                 const float* __restrict__ bv,
                                                 float* __restrict__ Q, float* __restrict__ Kp,
                                                 float* __restrict__ Vp) {
  __shared__ __align__(16) u16 Ah[2 * 128 * 32];
  __shared__ __align__(16) u16 Al[2 * 128 * 32];
  __shared__ __align__(16) u16 Bh[2 * 128 * 32];
  __shared__ __align__(16) u16 Bl[2 * 128 * 32];
  const int row0 = blockIdx.x * 128, col0 = blockIdx.y * 128;
  if (blockIdx.z == 0)
    gemm_body128<true, true>(QXH, QXL, WqH, WqL, bq, Q, Ah, Al, Bh, Bl, row0, col0);
  else if (blockIdx.z == 1)
    gemm_body128<true, true>(KXH, KXL, WkH, WkL, bk, Kp, Ah, Al, Bh, Bl, row0, col0);
  else
    gemm_body128<false, true>(VXH, VXH, WvH, WvH, bv, Vp, Ah, Al, Bh, Bl, row0, col0);
}

// ---------------------------------------------------------------------------
// Output GEMM (128x64): CH bf16 @ WoH + bo -> out.
// ---------------------------------------------------------------------------
__global__ __launch_bounds__(256) void gemm_out(const u16* __restrict__ CH,
                                                const u16* __restrict__ WoH,
                                                const float* __restrict__ bo,
                                                float* __restrict__ out) {
  __shared__ __align__(16) u16 Ah[128 * 32];
  __shared__ __align__(16) u16 Al[128 * 32];
  __shared__ __align__(16) u16 Bh[64 * 32];
  __shared__ __align__(16) u16 Bl[64 * 32];
  gemm_body64<false, false>(CH, CH, WoH, WoH, bo, out, Ah, Al, Bh, Bl,
                            blockIdx.x * 128, blockIdx.y * 64);
}

// ---------------------------------------------------------------------------
// M[b,h,q]. One wave per row; idx via LDS; bijective XCD swizzle for K L2-res.
// ---------------------------------------------------------------------------
__global__ __launch_bounds__(256) void m_kernel(const float* __restrict__ Q,
                                                const float* __restrict__ K,
                                                const int* __restrict__ idxs,
                                                float* __restrict__ M) {
  __shared__ int idl[4 * NS];
  const int tid = threadIdx.x;
  const int x = blockIdx.x & 7;        // XCD
  const int slot = blockIdx.x >> 3;
  const int bh = x * 4 + (slot >> 9);  // 4 bh-slices per XCD
  const int q0 = (slot & 511) * 4;

  if (tid < 4 * NS) idl[tid] = idxs[q0 * NS + tid];
  __syncthreads();

  const int lane = tid & 63, wid = tid >> 6;
  const int r = bh * SEQ + q0 + wid;
  const int g = lane >> 3;
  const int d8 = (lane & 7) * 8;
  const float* Qr = Q + (size_t)r * DH + d8;
  const float4 q0v = *(const float4*)Qr;
  const float4 q1v = *(const float4*)(Qr + 4);
  const float* Kbh = K + (size_t)bh * SEQ * DH;

  int ks[5];
#pragma unroll
  for (int p = 0; p < 5; p++) ks[p] = idl[wid * NS + g + 8 * p];
  float4 k0[5], k1[5];
#pragma unroll
  for (int p = 0; p < 5; p++) {
    const float* Kr = Kbh + (size_t)ks[p] * DH + d8;
    k0[p] = *(const float4*)Kr;
    k1[p] = *(const float4*)(Kr + 4);
  }
  float mx = -1e30f, sm = 0.f;
#pragma unroll
  for (int p = 0; p < 5; p++) {
    float acc = q0v.x * k0[p].x + q0v.y * k0[p].y + q0v.z * k0[p].z + q0v.w * k0[p].w +
                q1v.x * k1[p].x + q1v.y * k1[p].y + q1v.z * k1[p].z + q1v.w * k1[p].w;
    acc += __shfl_xor(acc, 1, 64);
    acc += __shfl_xor(acc, 2, 64);
    acc += __shfl_xor(acc, 4, 64);
    mx = fmaxf(mx, acc);
    sm += acc;
  }
#pragma unroll
  for (int o = 8; o <= 32; o <<= 1) {
    mx = fmaxf(mx, __shfl_xor(mx, o, 64));
    sm += __shfl_xor(sm, o, 64);
  }
  if (lane == 0) M[r] = mx - sm * (1.0f / (float)SEQ);
}

// ---------------------------------------------------------------------------
// Top-40 per (b,h) via bitonic sort of packed u64 keys. 1024 thr per (b,h).
// ---------------------------------------------------------------------------
__global__ __launch_bounds__(1024) void topk_kernel(const float* __restrict__ M,
                                                    int* __restrict__ Mtop) {
  __shared__ u64 keys[SEQ];
  const int bh = blockIdx.x, tid = threadIdx.x;
  const float* Mb = M + (size_t)bh * SEQ;
#pragma unroll
  for (int i = tid; i < SEQ; i += 1024) {
    unsigned ub = __float_as_uint(Mb[i]);
    ub ^= (ub >> 31) ? 0xFFFFFFFFu : 0x80000000u;
    keys[i] = ((u64)ub << 32) | (u64)(unsigned)~i;
  }
  __syncthreads();
  for (int k = 2; k <= SEQ; k <<= 1) {
    for (int j = k >> 1; j > 0; j >>= 1) {
#pragma unroll
      for (int i = tid; i < SEQ; i += 1024) {
        const int partner = i ^ j;
        if (partner > i) {
          const u64 a = keys[i], b = keys[partner];
          const bool desc = ((i & k) == 0);
          if (desc ? (a < b) : (a > b)) { keys[i] = b; keys[partner] = a; }
        }
      }
      __syncthreads();
    }
  }
  if (tid < NT) Mtop[bh * NT + tid] = (int)~(unsigned)keys[tid];
}

// ---------------------------------------------------------------------------
// V_sum two-stage.
// ---------------------------------------------------------------------------
__global__ __launch_bounds__(256) void vsum1_kernel(const float* __restrict__ V,
                                                    float* __restrict__ part) {
  __shared__ float sm[4][DH];
  const int bh = blockIdx.x, c = blockIdx.y, tid = threadIdx.x;
  const int dk = tid & 63, p = tid >> 6;
  const float* Vb = V + ((size_t)bh * SEQ + c * (SEQ / VCH)) * DH;
  float s = 0.f;
  for (int l = p; l < SEQ / VCH; l += 4) s += Vb[(size_t)l * DH + dk];
  sm[p][dk] = s;
  __syncthreads();
  if (p == 0)
    part[(size_t)(bh * VCH + c) * DH + dk] = sm[0][dk] + sm[1][dk] + sm[2][dk] + sm[3][dk];
}

__global__ __launch_bounds__(64) void vsum2_kernel(const float* __restrict__ part,
                                                   float* __restrict__ Vsum) {
  const int bh = blockIdx.x, dk = threadIdx.x;
  float s = 0.f;
#pragma unroll
  for (int c = 0; c < VCH; c++) s += part[(size_t)(bh * VCH + c) * DH + dk];
  Vsum[bh * DH + dk] = s;
}

// ---------------------------------------------------------------------------
// CH (B,L,D) bf16: V_sum broadcast (selected rows overwritten later).
// ---------------------------------------------------------------------------
__global__ __launch_bounds__(256) void ctxinit_kernel(const float* __restrict__ Vsum,
                                                      u16* __restrict__ CH) {
  const int idx = blockIdx.x * 256 + threadIdx.x;
  const int f = idx * 4;
  const int d = f & (DM - 1), b = f >> 20;
  float4 v = *(const float4*)&Vsum[b * DM + d];
  ushort4 h;
  h.x = f2bf(v.x); h.y = f2bf(v.y); h.z = f2bf(v.z); h.w = f2bf(v.w);
  ((ushort4*)CH)[idx] = h;
}

// ---------------------------------------------------------------------------
// Fused scores+softmax-partial+PV. Block (bh, sc, ug): 256 s-rows, 20 u's.
// Unnormalized: El = exp(Q_red·K/8); dpart = per-u row-sums; updp = El@V.
// ---------------------------------------------------------------------------
__global__ __launch_bounds__(256) void pv_fused_kernel(const float* __restrict__ Q,
                                                       const float* __restrict__ K,
                                                       const float* __restrict__ V,
                                                       const int* __restrict__ Mtop,
                                                       float* __restrict__ updp,
                                                       float* __restrict__ dpart) {
  __shared__ float El[UG * 256];  // 20KB: exp'd scores [u_local][sj]
  __shared__ float QV[4096];      // 16KB union: Qs (1280 fl) then Vl (4096 fl)
  const int bh = blockIdx.x, sc = blockIdx.y, tid = threadIdx.x;
  const int u0 = blockIdx.z * UG;
  const int s0 = sc * 256;
  const int wid = tid >> 6, lane = tid & 63;

  // stage Q_red rows [u0, u0+20)
  for (int i = tid; i < UG * DH; i += 256) {
    int u = i >> 6, dk = i & 63;
    int row = Mtop[bh * NT + u0 + u];
    QV[i] = Q[((size_t)bh * SEQ + row) * DH + dk];
  }
  // own K row into regs
  const float* Krow = K + ((size_t)bh * SEQ + s0 + tid) * DH;
  float4 kr[16];
#pragma unroll
  for (int g = 0; g < 16; g++) kr[g] = *(const float4*)&Krow[g * 4];
  __syncthreads();

  // scores + exp (Q reads are wave-broadcast)
  for (int u = 0; u < UG; u++) {
    float acc = 0.f;
#pragma unroll
    for (int g = 0; g < 16; g++) {
      float4 qv = *(const float4*)&QV[u * DH + g * 4];
      acc = fmaf(qv.x, kr[g].x, acc);
      acc = fmaf(qv.y, kr[g].y, acc);
      acc = fmaf(qv.z, kr[g].z, acc);
      acc = fmaf(qv.w, kr[g].w, acc);
    }
    El[u * 256 + tid] = __expf(acc * 0.125f);
  }
  __syncthreads();

  // per-u partial denominators (wave wid owns u = wid+4i, i<5)
#pragma unroll
  for (int i = 0; i < 5; i++) {
    const int u = wid + 4 * i;
    float p = El[u * 256 + lane] + El[u * 256 + 64 + lane] +
              El[u * 256 + 128 + lane] + El[u * 256 + 192 + lane];
#pragma unroll
    for (int o = 1; o <= 32; o <<= 1) p += __shfl_xor(p, o, 64);
    if (lane == 0) dpart[(bh * NSC + sc) * NT + u0 + u] = p;
  }

  // PV: acc[u=wid+4i][dk=lane] over 4 sub-steps of 64 rows
  float acc[5] = {};
  for (int st = 0; st < 4; st++) {
    __syncthreads();
#pragma unroll
    for (int i = 0; i < 16; i++) {
      int idx = tid + i * 256;
      int sj = idx >> 6, d2 = idx & 63;
      QV[idx] = V[((size_t)bh * SEQ + s0 + st * 64 + sj) * DH + d2];
    }
    __syncthreads();
    for (int g = 0; g < 16; g++) {
      float a[5][4];
#pragma unroll
      for (int i = 0; i < 5; i++) {
        float4 t = *(const float4*)&El[(wid + 4 * i) * 256 + st * 64 + g * 4];
        a[i][0] = t.x; a[i][1] = t.y; a[i][2] = t.z; a[i][3] = t.w;
      }
#pragma unroll
      for (int t = 0; t < 4; t++) {
        float v = QV[(g * 4 + t) * DH + lane];
#pragma unroll
        for (int i = 0; i < 5; i++) acc[i] = fmaf(a[i][t], v, acc[i]);
      }
    }
  }

#pragma unroll
  for (int i = 0; i < 5; i++) {
    int u = u0 + wid + 4 * i;
    updp[((size_t)(bh * NSC + sc) * NT + u) * DH + lane] = acc[i];
  }
}

// ---------------------------------------------------------------------------
// Combine chunk partials (fixed order), normalize, scatter bf16 into CH.
// ---------------------------------------------------------------------------
__global__ __launch_bounds__(256) void reduce_scatter_kernel(const float* __restrict__ updp,
                                                             const float* __restrict__ dpart,
                                                             const int* __restrict__ Mtop,
                                                             u16* __restrict__ CH) {
  const int bh = blockIdx.x;
  const int u = blockIdx.y * 4 + (threadIdx.x >> 6);
  const int dk = threadIdx.x & 63;
  float s = 0.f, d = 0.f;
#pragma unroll
  for (int sc = 0; sc < NSC; sc++) {
    s += updp[((size_t)(bh * NSC + sc) * NT + u) * DH + dk];
    d += dpart[(bh * NSC + sc) * NT + u];
  }
  const int row = Mtop[bh * NT + u];
  const int b = bh >> 3, h = bh & 7;
  CH[((size_t)b * SEQ + row) * DM + h * DH + dk] = f2bf(s / d);
}

// ---------------------------------------------------------------------------
extern "C" void kernel_launch(void* const* d_in, const int* in_sizes, int n_in,
                              void* d_out, int out_size, void* d_ws, size_t ws_size,
                              hipStream_t stream) {
  (void)in_sizes; (void)n_in; (void)out_size; (void)ws_size;
  const float* queries = (const float*)d_in[0];
  const float* keys    = (const float*)d_in[1];
  const float* values  = (const float*)d_in[2];
  const int* index_sample = (const int*)d_in[4];
  const float* Wq = (const float*)d_in[5];
  const float* bq = (const float*)d_in[6];
  const float* Wk = (const float*)d_in[7];
  const float* bk = (const float*)d_in[8];
  const float* Wv = (const float*)d_in[9];
  const float* bv = (const float*)d_in[10];
  const float* Wo = (const float*)d_in[11];
  const float* bo = (const float*)d_in[12];
  float* out = (float*)d_out;

  // ws layout (floats) — no aliasing.
  float* ws = (float*)d_ws;
  float* Q      = ws;
  float* Kp     = Q + (size_t)ROWS * DM;
  float* Vp     = Kp + (size_t)ROWS * DM;
  float* M      = Vp + (size_t)ROWS * DM;
  float* Vsum   = M + BHROWS;
  float* vpart  = Vsum + NB * NH * DH;
  float* dpart  = vpart + NB * NH * VCH * DH;
  float* updp   = dpart + (size_t)NSC * NB * NH * NT;
  int*   Mtop   = (int*)(updp + (size_t)NSC * NB * NH * NT * DH);
  u16* QXH = (u16*)(Mtop + NB * NH * NT + 64);
  u16* QXL = QXH + (size_t)ROWS * DM;
  u16* KXH = QXL + (size_t)ROWS * DM;
  u16* KXL = KXH + (size_t)ROWS * DM;
  u16* VXH = KXL + (size_t)ROWS * DM;
  u16* CH  = VXH + (size_t)ROWS * DM;
  u16* WqH = CH + (size_t)ROWS * DM;
  u16* WqL = WqH + (size_t)DM * DM;
  u16* WkH = WqL + (size_t)DM * DM;
  u16* WkL = WkH + (size_t)DM * DM;
  u16* WvH = WkL + (size_t)DM * DM;
  u16* WoH = WvH + (size_t)DM * DM;

  const int n4x = ROWS * DM / 4;

  cvt_all<<<dim3(n4x / 256, 1, 4), 256, 0, stream>>>(
      queries, keys, values, Wq, Wk, Wv, Wo,
      QXH, QXL, KXH, KXL, VXH, WqH, WqL, WkH, WkL, WvH, WoH);
  gemm_proj<<<dim3(ROWS / 128, DM / 128, 3), 256, 0, stream>>>(
      QXH, QXL, KXH, KXL, VXH, WqH, WqL, WkH, WkL, WvH, bq, bk, bv, Q, Kp, Vp);

  m_kernel<<<BHROWS / 4, 256, 0, stream>>>(Q, Kp, index_sample, M);
  topk_kernel<<<NB * NH, 1024, 0, stream>>>(M, Mtop);
  vsum1_kernel<<<dim3(NB * NH, VCH), 256, 0, stream>>>(Vp, vpart);
  vsum2_kernel<<<NB * NH, 64, 0, stream>>>(vpart, Vsum);
  ctxinit_kernel<<<(ROWS * DM / 4) / 256, 256, 0, stream>>>(Vsum, CH);
  pv_fused_kernel<<<dim3(NB * NH, NSC, NT / UG), 256, 0, stream>>>(Q, Kp, Vp, Mtop, updp, dpart);
  reduce_scatter_kernel<<<dim3(NB * NH, NT / 4), 256, 0, stream>>>(updp, dpart, Mtop, CH);

  gemm_out<<<dim3(ROWS / 128, DM / 64), 256, 0, stream>>>(CH, WoH, bo, out);
}